// Round 13
// baseline (329.800 us; speedup 1.0000x reference)
//
#include <hip/hip_runtime.h>
#include <math.h>

#define GRIDC  48
#define CELLS  (GRIDC*GRIDC*GRIDC)   // 110592
#define NBLK1  (CELLS/1024)          // 108 scan1 blocks per job
#define EXT    96.0f                 // grid covers [-96,96]^3 (4.8 sigma)
#define CSZ    4.0f
#define INVC   0.25f
#define STOP_MARGIN 0.1f             // >> max |computed sq - math sq| (~0.01)

// ---------- rounding-exact helpers (match numpy exactly) ----------
__device__ __forceinline__ float mul_rn(float a, float b) {
#pragma clang fp contract(off)
    return a * b;
}
__device__ __forceinline__ float add_rn(float a, float b) {
#pragma clang fp contract(off)
    return a + b;
}
__device__ __forceinline__ float sumsq3(float x, float y, float z) {
    return add_rn(add_rn(mul_rn(x, x), mul_rn(y, y)), mul_rn(z, z));
}
// EXACT sq = (||a||^2 + ||b||^2) - 2*dot — bit-matches the reference.
__device__ __forceinline__ float pair_sq(float a0, float a1, float a2, float an,
                                         float bx, float by, float bz, float bw) {
    const float dot = __builtin_fmaf(a2, bz,
                      __builtin_fmaf(a1, by, mul_rn(a0, bx)));
    return __builtin_fmaf(-2.0f, dot, add_rn(an, bw));
}
// lexicographic (sq, idx) top-3 insert — order-independent, == lax.top_k.
// No dedupe: every box scan visits each point exactly once (fresh state per t).
__device__ __forceinline__ void lex3_push(float& d0, float& d1, float& d2,
                                          int& i0, int& i1, int& i2,
                                          float sq, int idx) {
    const bool l0 = (sq < d0) || (sq == d0 && idx < i0);
    const bool l1 = (sq < d1) || (sq == d1 && idx < i1);
    const bool l2 = (sq < d2) || (sq == d2 && idx < i2);
    i2 = l1 ? i1 : (l2 ? idx : i2);
    d2 = l1 ? d1 : (l2 ? sq  : d2);
    i1 = l0 ? i0 : (l1 ? idx : i1);
    d1 = l0 ? d0 : (l1 ? sq  : d1);
    i0 = l0 ? idx : i0;
    d0 = l0 ? sq  : d0;
}
__device__ __forceinline__ void cell_coords(float x, float y, float z,
                                            int& cx, int& cy, int& cz) {
    cx = min(max((int)floorf((x + EXT) * INVC), 0), GRIDC - 1);
    cy = min(max((int)floorf((y + EXT) * INVC), 0), GRIDC - 1);
    cz = min(max((int)floorf((z + EXT) * INVC), 0), GRIDC - 1);
}

// ---------- binning: refs (y==0) AND queries (y==1) share kernels ----------
__global__ __launch_bounds__(256) void zero_kernel(int* __restrict__ a) {
    a[blockIdx.x * 256 + threadIdx.x] = 0;   // grid covers 2*CELLS
}

__global__ __launch_bounds__(256) void count_kernel(
    const float* __restrict__ r, const float* __restrict__ q,
    int* __restrict__ counts, int M, int N)
{
    const int job = blockIdx.y;
    const float* src = job ? q : r;
    const int n = job ? N : M;
    const int i = blockIdx.x * 256 + threadIdx.x;
    if (i < n) {
        int cx, cy, cz;
        cell_coords(src[3 * i], src[3 * i + 1], src[3 * i + 2], cx, cy, cz);
        atomicAdd(&counts[job * CELLS + (cz * GRIDC + cy) * GRIDC + cx], 1);
    }
}

// scan1: per-block (1024 cells) exclusive scan + block total; 2 jobs via y.
__global__ __launch_bounds__(256) void scan1_kernel(
    const int* __restrict__ counts, int* __restrict__ cellLoc,
    int* __restrict__ bsum)
{
    __shared__ int arr[256];
    const int tid = threadIdx.x;
    const int base = blockIdx.y * CELLS + blockIdx.x * 1024 + tid * 4;
    const int4 c = *(const int4*)(counts + base);
    const int t1 = c.x, t2 = c.x + c.y, t3 = t2 + c.z, tot = t3 + c.w;
    arr[tid] = tot;
    __syncthreads();
    for (int off = 1; off < 256; off <<= 1) {
        const int w = (tid >= off) ? arr[tid - off] : 0;
        __syncthreads();
        arr[tid] += w;
        __syncthreads();
    }
    const int excl = arr[tid] - tot;
    *(int4*)(cellLoc + base) = make_int4(excl, excl + t1, excl + t2, excl + t3);
    if (tid == 255) bsum[blockIdx.y * 128 + blockIdx.x] = arr[255];
}

__global__ __launch_bounds__(128) void scan2_kernel(
    const int* __restrict__ bsum, int* __restrict__ bscan)
{
    __shared__ int arr[128];
    const int tid = threadIdx.x;
    const int off0 = blockIdx.x * 128;       // job select
    const int v = (tid < NBLK1) ? bsum[off0 + tid] : 0;
    arr[tid] = v;
    __syncthreads();
    for (int off = 1; off < 128; off <<= 1) {
        const int w = (tid >= off) ? arr[tid - off] : 0;
        __syncthreads();
        arr[tid] += w;
        __syncthreads();
    }
    if (tid < NBLK1) bscan[off0 + tid] = arr[tid] - v;
}

__global__ __launch_bounds__(256) void scan3_kernel(
    const int* __restrict__ cellLoc, const int* __restrict__ bscan,
    int* __restrict__ cellStart, int* __restrict__ cellCur)
{
    const int i = blockIdx.x * 256 + threadIdx.x;
    const int g = blockIdx.y * CELLS + i;
    const int v = cellLoc[g] + bscan[blockIdx.y * 128 + (i >> 10)];
    cellStart[g] = v;
    cellCur[g] = v;
}

// scatter: refs -> pts4/pidx; queries -> qorder (sorted-position -> qi).
__global__ __launch_bounds__(256) void scatter_kernel(
    const float* __restrict__ r, const float* __restrict__ q,
    int* __restrict__ cellCur, float4* __restrict__ pts4,
    int* __restrict__ pidx, int* __restrict__ qorder, int M, int N)
{
    const int job = blockIdx.y;
    const float* src = job ? q : r;
    const int n = job ? N : M;
    const int i = blockIdx.x * 256 + threadIdx.x;
    if (i < n) {
        const float x = src[3 * i], y = src[3 * i + 1], z = src[3 * i + 2];
        int cx, cy, cz;
        cell_coords(x, y, z, cx, cy, cz);
        const int pos = atomicAdd(&cellCur[job * CELLS + (cz * GRIDC + cy) * GRIDC + cx], 1);
        if (job) {
            qorder[pos] = i;
        } else {
            pts4[pos] = make_float4(x, y, z, sumsq3(x, y, z));  // bw exact
            pidx[pos] = i;
        }
    }
}

// ---------- KNN: THREAD per query, queries in cell-sorted order ----------
// Sorted order => adjacent lanes scan the same cells (shared cache lines,
// wave-coherent trip counts/branches). Scalar per-thread state: no shuffles,
// no butterflies, no idle-lane runs. Expanding box t=1,2,... with FRESH
// top-3 state each t (each box visits each point once -> no dedupe).
// Stop: own d2 (exact 3rd-smallest computed sq in box) <= bnd^2 - margin,
// bnd = distance to unscanned half-spaces (clipped at grid edges; clamped
// boundary points lie beyond edge cells -> conservative).
__global__ __launch_bounds__(64) void knn_kernel(
    const float* __restrict__ q, const float4* __restrict__ pts4,
    const int* __restrict__ pidx, const int* __restrict__ cellStart,
    const int* __restrict__ counts, const int* __restrict__ qorder,
    const float* __restrict__ flow, float* __restrict__ out)
{
    const int gid = blockIdx.x * 64 + threadIdx.x;   // sorted position
    const int qi = qorder[gid];

    const float a0 = q[qi * 3 + 0];
    const float a1 = q[qi * 3 + 1];
    const float a2 = q[qi * 3 + 2];
    const float an = sumsq3(a0, a1, a2);
    int cx, cy, cz;
    cell_coords(a0, a1, a2, cx, cy, cz);

    float d0 = __builtin_inff(), d1 = __builtin_inff(), d2 = __builtin_inff();
    int   i0 = 0x7fffffff, i1 = 0x7fffffff, i2 = 0x7fffffff;

    for (int t = 1; t <= GRIDC; ++t) {
        const int xlo = max(cx - t, 0), xhi = min(cx + t, GRIDC - 1);
        const int ylo = max(cy - t, 0), yhi = min(cy + t, GRIDC - 1);
        const int zlo = max(cz - t, 0), zhi = min(cz + t, GRIDC - 1);

        // fresh state for this box
        d0 = d1 = d2 = __builtin_inff();
        i0 = i1 = i2 = 0x7fffffff;

        for (int zz = zlo; zz <= zhi; ++zz) {
            for (int yy = ylo; yy <= yhi; ++yy) {
                const int cb = (zz * GRIDC + yy) * GRIDC;
                const int st = cellStart[cb + xlo];
                const int en = cellStart[cb + xhi] + counts[cb + xhi];
                for (int p = st; p < en; ++p) {
                    const float4 pt = pts4[p];
                    const int idx = pidx[p];
                    const float sq = pair_sq(a0, a1, a2, an,
                                             pt.x, pt.y, pt.z, pt.w);
                    lex3_push(d0, d1, d2, i0, i1, i2, sq, idx);
                }
            }
        }

        // distance bound to the unscanned region (6 clipped half-spaces)
        float bnd = __builtin_inff();
        if (xlo > 0)         bnd = fminf(bnd, a0 - ((float)xlo * CSZ - EXT));
        if (xhi < GRIDC - 1) bnd = fminf(bnd, ((float)(xhi + 1) * CSZ - EXT) - a0);
        if (ylo > 0)         bnd = fminf(bnd, a1 - ((float)ylo * CSZ - EXT));
        if (yhi < GRIDC - 1) bnd = fminf(bnd, ((float)(yhi + 1) * CSZ - EXT) - a1);
        if (zlo > 0)         bnd = fminf(bnd, a2 - ((float)zlo * CSZ - EXT));
        if (zhi < GRIDC - 1) bnd = fminf(bnd, ((float)(zhi + 1) * CSZ - EXT) - a2);

        if (__builtin_isinf(bnd)) break;                // whole grid scanned
        if (d2 <= __builtin_fmaf(bnd, bnd, -STOP_MARGIN)) break;
    }

    // epilogue (rounding-exact, matches reference op order)
    {
        const float t0 = sqrtf(fmaxf(d0, 1e-12f));
        const float t1 = sqrtf(fmaxf(d1, 1e-12f));
        const float t2 = sqrtf(fmaxf(d2, 1e-12f));
        const float w0r = 1.0f / add_rn(t0, 1e-8f);
        const float w1r = 1.0f / add_rn(t1, 1e-8f);
        const float w2r = 1.0f / add_rn(t2, 1e-8f);
        const float wsum = add_rn(add_rn(w0r, w1r), w2r);
        const float w0 = w0r / wsum;
        const float w1 = w1r / wsum;
        const float w2 = w2r / wsum;

        const float f00 = flow[3 * i0 + 0], f01 = flow[3 * i0 + 1], f02 = flow[3 * i0 + 2];
        const float f10 = flow[3 * i1 + 0], f11 = flow[3 * i1 + 1], f12 = flow[3 * i1 + 2];
        const float f20 = flow[3 * i2 + 0], f21 = flow[3 * i2 + 1], f22 = flow[3 * i2 + 2];

        out[qi * 3 + 0] = add_rn(add_rn(mul_rn(w0, f00), mul_rn(w1, f10)), mul_rn(w2, f20));
        out[qi * 3 + 1] = add_rn(add_rn(mul_rn(w0, f01), mul_rn(w1, f11)), mul_rn(w2, f21));
        out[qi * 3 + 2] = add_rn(add_rn(mul_rn(w0, f02), mul_rn(w1, f12)), mul_rn(w2, f22));
    }
}

extern "C" void kernel_launch(void* const* d_in, const int* in_sizes, int n_in,
                              void* d_out, int out_size, void* d_ws, size_t ws_size,
                              hipStream_t stream) {
    const float* q    = (const float*)d_in[0];
    const float* r    = (const float*)d_in[1];
    const float* flow = (const float*)d_in[2];
    // d_in[3] is k (==3), hard-coded.

    const int N = in_sizes[0] / 3;
    const int M = in_sizes[1] / 3;

    // ws layout (~3.6 MB):
    int* counts    = (int*)d_ws;                 // 2*CELLS (refs | queries)
    int* cellLoc   = counts + 2 * CELLS;         // 2*CELLS
    int* bsum      = cellLoc + 2 * CELLS;        // 256 (128 per job)
    int* bscan     = bsum + 256;                 // 256
    int* cellStart = bscan + 256;                // 2*CELLS
    int* cellCur   = cellStart + 2 * CELLS;      // 2*CELLS
    float4* pts4   = (float4*)(cellCur + 2 * CELLS);  // M (16B-aligned)
    int* pidx      = (int*)(pts4 + M);           // M
    int* qorder    = pidx + M;                   // N
    (void)ws_size;

    const int mb = (max(M, N) + 255) / 256;

    zero_kernel<<<2 * CELLS / 256, 256, 0, stream>>>(counts);
    count_kernel<<<dim3(mb, 2), 256, 0, stream>>>(r, q, counts, M, N);
    scan1_kernel<<<dim3(NBLK1, 2), 256, 0, stream>>>(counts, cellLoc, bsum);
    scan2_kernel<<<2, 128, 0, stream>>>(bsum, bscan);
    scan3_kernel<<<dim3(CELLS / 256, 2), 256, 0, stream>>>(cellLoc, bscan,
                                                           cellStart, cellCur);
    scatter_kernel<<<dim3(mb, 2), 256, 0, stream>>>(r, q, cellCur, pts4,
                                                    pidx, qorder, M, N);

    knn_kernel<<<N / 64, 64, 0, stream>>>(q, pts4, pidx, cellStart, counts,
                                          qorder, flow, (float*)d_out);
}

// Round 14
// 150.125 us; speedup vs baseline: 2.1968x; 2.1968x over previous
//
#include <hip/hip_runtime.h>
#include <math.h>

#define GRIDC  48
#define CELLS  (GRIDC*GRIDC*GRIDC)   // 110592
#define NBLK1  (CELLS/1024)          // 108 scan1 blocks per job
#define EXT    96.0f                 // grid covers [-96,96]^3 (4.8 sigma)
#define CSZ    4.0f
#define INVC   0.25f
#define STOP_MARGIN 0.1f             // >> max |computed sq - math sq| (~0.01)
#define L      8                     // lanes per query (aligned subgroup)

// ---------- rounding-exact helpers (match numpy exactly) ----------
__device__ __forceinline__ float mul_rn(float a, float b) {
#pragma clang fp contract(off)
    return a * b;
}
__device__ __forceinline__ float add_rn(float a, float b) {
#pragma clang fp contract(off)
    return a + b;
}
__device__ __forceinline__ float sumsq3(float x, float y, float z) {
    return add_rn(add_rn(mul_rn(x, x), mul_rn(y, y)), mul_rn(z, z));
}
// EXACT sq = (||a||^2 + ||b||^2) - 2*dot — bit-matches the reference.
__device__ __forceinline__ float pair_sq(float a0, float a1, float a2, float an,
                                         float bx, float by, float bz, float bw) {
    const float dot = __builtin_fmaf(a2, bz,
                      __builtin_fmaf(a1, by, mul_rn(a0, bx)));
    return __builtin_fmaf(-2.0f, dot, add_rn(an, bw));
}
// lexicographic (sq, idx) top-3 insert — order-independent, == lax.top_k.
__device__ __forceinline__ void lex3_push(float& d0, float& d1, float& d2,
                                          int& i0, int& i1, int& i2,
                                          float sq, int idx) {
    const bool l0 = (sq < d0) || (sq == d0 && idx < i0);
    const bool l1 = (sq < d1) || (sq == d1 && idx < i1);
    const bool l2 = (sq < d2) || (sq == d2 && idx < i2);
    i2 = l1 ? i1 : (l2 ? idx : i2);
    d2 = l1 ? d1 : (l2 ? sq  : d2);
    i1 = l0 ? i0 : (l1 ? idx : i1);
    d1 = l0 ? d0 : (l1 ? sq  : d1);
    i0 = l0 ? idx : i0;
    d0 = l0 ? sq  : d0;
}
__device__ __forceinline__ void cell_coords(float x, float y, float z,
                                            int& cx, int& cy, int& cz) {
    cx = min(max((int)floorf((x + EXT) * INVC), 0), GRIDC - 1);
    cy = min(max((int)floorf((y + EXT) * INVC), 0), GRIDC - 1);
    cz = min(max((int)floorf((z + EXT) * INVC), 0), GRIDC - 1);
}

// ---------- binning: refs (y==0) AND queries (y==1) share kernels ----------
__global__ __launch_bounds__(256) void zero_kernel(int* __restrict__ a) {
    a[blockIdx.x * 256 + threadIdx.x] = 0;   // grid covers 2*CELLS
}

__global__ __launch_bounds__(256) void count_kernel(
    const float* __restrict__ r, const float* __restrict__ q,
    int* __restrict__ counts, int M, int N)
{
    const int job = blockIdx.y;
    const float* src = job ? q : r;
    const int n = job ? N : M;
    const int i = blockIdx.x * 256 + threadIdx.x;
    if (i < n) {
        int cx, cy, cz;
        cell_coords(src[3 * i], src[3 * i + 1], src[3 * i + 2], cx, cy, cz);
        atomicAdd(&counts[job * CELLS + (cz * GRIDC + cy) * GRIDC + cx], 1);
    }
}

__global__ __launch_bounds__(256) void scan1_kernel(
    const int* __restrict__ counts, int* __restrict__ cellLoc,
    int* __restrict__ bsum)
{
    __shared__ int arr[256];
    const int tid = threadIdx.x;
    const int base = blockIdx.y * CELLS + blockIdx.x * 1024 + tid * 4;
    const int4 c = *(const int4*)(counts + base);
    const int t1 = c.x, t2 = c.x + c.y, t3 = t2 + c.z, tot = t3 + c.w;
    arr[tid] = tot;
    __syncthreads();
    for (int off = 1; off < 256; off <<= 1) {
        const int w = (tid >= off) ? arr[tid - off] : 0;
        __syncthreads();
        arr[tid] += w;
        __syncthreads();
    }
    const int excl = arr[tid] - tot;
    *(int4*)(cellLoc + base) = make_int4(excl, excl + t1, excl + t2, excl + t3);
    if (tid == 255) bsum[blockIdx.y * 128 + blockIdx.x] = arr[255];
}

__global__ __launch_bounds__(128) void scan2_kernel(
    const int* __restrict__ bsum, int* __restrict__ bscan)
{
    __shared__ int arr[128];
    const int tid = threadIdx.x;
    const int off0 = blockIdx.x * 128;       // job select
    const int v = (tid < NBLK1) ? bsum[off0 + tid] : 0;
    arr[tid] = v;
    __syncthreads();
    for (int off = 1; off < 128; off <<= 1) {
        const int w = (tid >= off) ? arr[tid - off] : 0;
        __syncthreads();
        arr[tid] += w;
        __syncthreads();
    }
    if (tid < NBLK1) bscan[off0 + tid] = arr[tid] - v;
}

__global__ __launch_bounds__(256) void scan3_kernel(
    const int* __restrict__ cellLoc, const int* __restrict__ bscan,
    int* __restrict__ cellStart, int* __restrict__ cellCur)
{
    const int i = blockIdx.x * 256 + threadIdx.x;
    const int g = blockIdx.y * CELLS + i;
    const int v = cellLoc[g] + bscan[blockIdx.y * 128 + (i >> 10)];
    cellStart[g] = v;
    cellCur[g] = v;
}

__global__ __launch_bounds__(256) void scatter_kernel(
    const float* __restrict__ r, const float* __restrict__ q,
    int* __restrict__ cellCur, float4* __restrict__ pts4,
    int* __restrict__ pidx, int* __restrict__ qorder, int M, int N)
{
    const int job = blockIdx.y;
    const float* src = job ? q : r;
    const int n = job ? N : M;
    const int i = blockIdx.x * 256 + threadIdx.x;
    if (i < n) {
        const float x = src[3 * i], y = src[3 * i + 1], z = src[3 * i + 2];
        int cx, cy, cz;
        cell_coords(x, y, z, cx, cy, cz);
        const int pos = atomicAdd(&cellCur[job * CELLS + (cz * GRIDC + cy) * GRIDC + cx], 1);
        if (job) {
            qorder[pos] = i;
        } else {
            pts4[pos] = make_float4(x, y, z, sumsq3(x, y, z));  // bw exact
            pidx[pos] = i;
        }
    }
}

// ---------- summed-area table over ref cell counts (3 prefix passes) ----
__global__ __launch_bounds__(256) void sat_x_kernel(
    const int* __restrict__ counts, int* __restrict__ sat)
{
    const int line = blockIdx.x * 256 + threadIdx.x;   // (z*48+y)
    if (line < GRIDC * GRIDC) {
        const int base = line * GRIDC;
        int acc = 0;
        for (int x = 0; x < GRIDC; ++x) { acc += counts[base + x]; sat[base + x] = acc; }
    }
}
__global__ __launch_bounds__(256) void sat_y_kernel(int* __restrict__ sat)
{
    const int line = blockIdx.x * 256 + threadIdx.x;   // (z*48+x)
    if (line < GRIDC * GRIDC) {
        const int z = line / GRIDC, x = line - (line / GRIDC) * GRIDC;
        int acc = 0;
        for (int y = 0; y < GRIDC; ++y) {
            const int id = (z * GRIDC + y) * GRIDC + x;
            acc += sat[id]; sat[id] = acc;
        }
    }
}
__global__ __launch_bounds__(256) void sat_z_kernel(int* __restrict__ sat)
{
    const int line = blockIdx.x * 256 + threadIdx.x;   // (y*48+x)
    if (line < GRIDC * GRIDC) {
        int acc = 0;
        for (int z = 0; z < GRIDC; ++z) {
            const int id = z * GRIDC * GRIDC + line;
            acc += sat[id]; sat[id] = acc;
        }
    }
}

// ---------- KNN: 8 LANES per query, sorted queries, SAT jump-start ------
// Group of L=8 aligned lanes per query (131072 threads = 8 waves/CU).
// (1) SAT probes find the first box with >=3 points: each lane loads one
//     inclusion-exclusion corner, 3-stage shfl_xor reduce => O(1) per probe
//     (kills R12's quadratic empty-box tail).
// (2) Box scan: flattened rows strided across the 8 lanes (disjoint =>
//     no dedupe); per-lane lex3 on exact reference-rounded sq; 3-stage
//     shfl_xor lex3 merge gives all lanes the group top-3.
// (3) Stop when d2 <= bnd^2 - margin (bnd = distance to unscanned
//     half-spaces, clipped at edges; clamped points stay conservative),
//     else grow t with FRESH state. Sub-lane 0 writes the epilogue.
__global__ __launch_bounds__(256) void knn_kernel(
    const float* __restrict__ q, const float4* __restrict__ pts4,
    const int* __restrict__ pidx, const int* __restrict__ cellStart,
    const int* __restrict__ counts, const int* __restrict__ sat,
    const int* __restrict__ qorder, const float* __restrict__ flow,
    float* __restrict__ out)
{
    const int sub = threadIdx.x & (L - 1);
    const int gid = blockIdx.x * (256 / L) + (threadIdx.x >> 3);  // sorted pos
    const int qi = qorder[gid];

    const float a0 = q[qi * 3 + 0];
    const float a1 = q[qi * 3 + 1];
    const float a2 = q[qi * 3 + 2];
    const float an = sumsq3(a0, a1, a2);
    int cx, cy, cz;
    cell_coords(a0, a1, a2, cx, cy, cz);

    // --- (1) jump-start t via SAT box counts ---
    int t = 1;
    for (;; ++t) {
        const int xlo = max(cx - t, 0), xhi = min(cx + t, GRIDC - 1);
        const int ylo = max(cy - t, 0), yhi = min(cy + t, GRIDC - 1);
        const int zlo = max(cz - t, 0), zhi = min(cz + t, GRIDC - 1);
        // corner for this lane: bit0->x, bit1->y, bit2->z (hi if set, lo-1 if not)
        const int xx = (sub & 1) ? xhi : xlo - 1;
        const int yy = (sub & 2) ? yhi : ylo - 1;
        const int zz = (sub & 4) ? zhi : zlo - 1;
        int v = 0;
        if (xx >= 0 && yy >= 0 && zz >= 0)
            v = sat[(zz * GRIDC + yy) * GRIDC + xx];
        const int sgn = ((3 - __popc(sub)) & 1) ? -1 : 1;
        v *= sgn;
        v += __shfl_xor(v, 1);
        v += __shfl_xor(v, 2);
        v += __shfl_xor(v, 4);          // all 8 lanes: box count
        const bool full = (xlo == 0) && (xhi == GRIDC - 1) && (ylo == 0) &&
                          (yhi == GRIDC - 1) && (zlo == 0) && (zhi == GRIDC - 1);
        if (v >= 3 || full) break;
    }

    // --- (2)+(3) scan boxes until the bound certifies the top-3 ---
    float d0, d1, d2;
    int   i0, i1, i2;
    for (;; ++t) {
        const int xlo = max(cx - t, 0), xhi = min(cx + t, GRIDC - 1);
        const int ylo = max(cy - t, 0), yhi = min(cy + t, GRIDC - 1);
        const int zlo = max(cz - t, 0), zhi = min(cz + t, GRIDC - 1);
        const int ny = yhi - ylo + 1;
        const int nrow = ny * (zhi - zlo + 1);

        d0 = d1 = d2 = __builtin_inff();
        i0 = i1 = i2 = 0x7fffffff;

        for (int ri = sub; ri < nrow; ri += L) {   // disjoint rows per lane
            const int zz = ri / ny;
            const int yy = ri - zz * ny;
            const int cb = ((zlo + zz) * GRIDC + (ylo + yy)) * GRIDC;
            const int st = cellStart[cb + xlo];
            const int en = cellStart[cb + xhi] + counts[cb + xhi];
            for (int p = st; p < en; ++p) {
                const float4 pt = pts4[p];
                const int idx = pidx[p];
                const float sq = pair_sq(a0, a1, a2, an, pt.x, pt.y, pt.z, pt.w);
                lex3_push(d0, d1, d2, i0, i1, i2, sq, idx);
            }
        }

        // 3-stage lex3 merge within the 8-lane group (disjoint sets)
#pragma unroll
        for (int m = 1; m < L; m <<= 1) {
            const float e0 = __shfl_xor(d0, m);
            const float e1 = __shfl_xor(d1, m);
            const float e2 = __shfl_xor(d2, m);
            const int   j0 = __shfl_xor(i0, m);
            const int   j1 = __shfl_xor(i1, m);
            const int   j2 = __shfl_xor(i2, m);
            lex3_push(d0, d1, d2, i0, i1, i2, e0, j0);
            lex3_push(d0, d1, d2, i0, i1, i2, e1, j1);
            lex3_push(d0, d1, d2, i0, i1, i2, e2, j2);
        }

        // distance bound to the unscanned region (6 clipped half-spaces)
        float bnd = __builtin_inff();
        if (xlo > 0)         bnd = fminf(bnd, a0 - ((float)xlo * CSZ - EXT));
        if (xhi < GRIDC - 1) bnd = fminf(bnd, ((float)(xhi + 1) * CSZ - EXT) - a0);
        if (ylo > 0)         bnd = fminf(bnd, a1 - ((float)ylo * CSZ - EXT));
        if (yhi < GRIDC - 1) bnd = fminf(bnd, ((float)(yhi + 1) * CSZ - EXT) - a1);
        if (zlo > 0)         bnd = fminf(bnd, a2 - ((float)zlo * CSZ - EXT));
        if (zhi < GRIDC - 1) bnd = fminf(bnd, ((float)(zhi + 1) * CSZ - EXT) - a2);

        if (__builtin_isinf(bnd)) break;                // whole grid scanned
        if (d2 <= __builtin_fmaf(bnd, bnd, -STOP_MARGIN)) break;
    }

    // --- epilogue (rounding-exact, matches reference op order) ---
    if (sub == 0) {
        const float t0 = sqrtf(fmaxf(d0, 1e-12f));
        const float t1 = sqrtf(fmaxf(d1, 1e-12f));
        const float t2 = sqrtf(fmaxf(d2, 1e-12f));
        const float w0r = 1.0f / add_rn(t0, 1e-8f);
        const float w1r = 1.0f / add_rn(t1, 1e-8f);
        const float w2r = 1.0f / add_rn(t2, 1e-8f);
        const float wsum = add_rn(add_rn(w0r, w1r), w2r);
        const float w0 = w0r / wsum;
        const float w1 = w1r / wsum;
        const float w2 = w2r / wsum;

        const float f00 = flow[3 * i0 + 0], f01 = flow[3 * i0 + 1], f02 = flow[3 * i0 + 2];
        const float f10 = flow[3 * i1 + 0], f11 = flow[3 * i1 + 1], f12 = flow[3 * i1 + 2];
        const float f20 = flow[3 * i2 + 0], f21 = flow[3 * i2 + 1], f22 = flow[3 * i2 + 2];

        out[qi * 3 + 0] = add_rn(add_rn(mul_rn(w0, f00), mul_rn(w1, f10)), mul_rn(w2, f20));
        out[qi * 3 + 1] = add_rn(add_rn(mul_rn(w0, f01), mul_rn(w1, f11)), mul_rn(w2, f21));
        out[qi * 3 + 2] = add_rn(add_rn(mul_rn(w0, f02), mul_rn(w1, f12)), mul_rn(w2, f22));
    }
}

extern "C" void kernel_launch(void* const* d_in, const int* in_sizes, int n_in,
                              void* d_out, int out_size, void* d_ws, size_t ws_size,
                              hipStream_t stream) {
    const float* q    = (const float*)d_in[0];
    const float* r    = (const float*)d_in[1];
    const float* flow = (const float*)d_in[2];
    // d_in[3] is k (==3), hard-coded.

    const int N = in_sizes[0] / 3;
    const int M = in_sizes[1] / 3;

    // ws layout (~4 MB):
    int* counts    = (int*)d_ws;                 // 2*CELLS (refs | queries)
    int* cellLoc   = counts + 2 * CELLS;         // 2*CELLS
    int* bsum      = cellLoc + 2 * CELLS;        // 256 (128 per job)
    int* bscan     = bsum + 256;                 // 256
    int* cellStart = bscan + 256;                // 2*CELLS
    int* cellCur   = cellStart + 2 * CELLS;      // 2*CELLS
    int* sat       = cellCur + 2 * CELLS;        // CELLS
    float4* pts4   = (float4*)(sat + CELLS);     // M (offset 16B-aligned)
    int* pidx      = (int*)(pts4 + M);           // M
    int* qorder    = pidx + M;                   // N
    (void)ws_size;

    const int mb = (max(M, N) + 255) / 256;
    const int lines = (GRIDC * GRIDC + 255) / 256;   // 9 blocks

    zero_kernel<<<2 * CELLS / 256, 256, 0, stream>>>(counts);
    count_kernel<<<dim3(mb, 2), 256, 0, stream>>>(r, q, counts, M, N);
    scan1_kernel<<<dim3(NBLK1, 2), 256, 0, stream>>>(counts, cellLoc, bsum);
    scan2_kernel<<<2, 128, 0, stream>>>(bsum, bscan);
    scan3_kernel<<<dim3(CELLS / 256, 2), 256, 0, stream>>>(cellLoc, bscan,
                                                           cellStart, cellCur);
    scatter_kernel<<<dim3(mb, 2), 256, 0, stream>>>(r, q, cellCur, pts4,
                                                    pidx, qorder, M, N);
    sat_x_kernel<<<lines, 256, 0, stream>>>(counts, sat);
    sat_y_kernel<<<lines, 256, 0, stream>>>(sat);
    sat_z_kernel<<<lines, 256, 0, stream>>>(sat);

    knn_kernel<<<N * L / 256, 256, 0, stream>>>(q, pts4, pidx, cellStart,
                                                counts, sat, qorder, flow,
                                                (float*)d_out);
}